// Round 4
// baseline (227.822 us; speedup 1.0000x reference)
//
#include <hip/hip_runtime.h>
#include <cstdint>
#include <cstddef>

// LogMM_19490561589867: x [8,2048,1024] f32, matrix [1024,1024] f32
// out = log(max(x @ matrix, tiny))  [8,2048,1024] f32
// Round-11: fix round-10's three measured failures while keeping its core
// (A read from HBM exactly once, converted in-register to fp8 LDS panel):
//  1) 512 threads (8 waves = 2/SIMD) instead of 256 (1/SIMD, occupancy 10%).
//  2) Epilogue back to LDS-staged f32x4 nontemporal stores (round-0..2
//     proven WRITE_SIZE == ideal); round-10's scalar nt stores measured
//     188MB writes (+3x) and ~64MB C read-for-merge fetch.
//  3) lgkm-only drains in the epilogue so the cross-chunk B prefetch and
//     C stores stay in flight; counted vmcnt (4 / 12-after-epilogue).
// Numerics identical: fp8 e4m3 RNE quantized GEMM, absmax 0.03125 (floor).
#define M_GLOB 16384
#define N_GLOB 1024
#define K_GLOB 1024

#define BM   64    // block rows (A panel in LDS)
#define BNC  256   // n-chunk cols per accumulation pass
#define NCH  4     // chunks (1024/256)
#define NKT  8     // K tiles of 128 fp8 bytes
#define NT   32    // NCH*NKT pipeline steps

typedef unsigned char  u8;
typedef unsigned short u16;
typedef __attribute__((ext_vector_type(4))) float  f32x4;
typedef __attribute__((ext_vector_type(16))) float f32x16;
typedef __attribute__((ext_vector_type(4))) unsigned int  u32x4;
typedef __attribute__((ext_vector_type(2))) unsigned int  u32x2;
typedef __attribute__((ext_vector_type(8))) int  i32x8;
typedef __attribute__((ext_vector_type(8))) __bf16 bf16x8;

// truncating pack (fallback fused path — round-1 proven numerics)
static __device__ __forceinline__ unsigned pack2_bf16(float lo, float hi) {
    unsigned bl = __builtin_bit_cast(unsigned, lo);
    unsigned bh = __builtin_bit_cast(unsigned, hi);
    return (bh & 0xFFFF0000u) | (bl >> 16);
}

// 4 fp32 -> 4 fp8 e4m3 bytes (HW RNE, OCP on gfx950)
static __device__ __forceinline__ unsigned cvt4_fp8(float a, float b, float c, float d) {
    int w = __builtin_amdgcn_cvt_pk_fp8_f32(a, b, 0, false);
    w = __builtin_amdgcn_cvt_pk_fp8_f32(c, d, w, true);
    return (unsigned)w;
}

// Raw workgroup barrier: compiler memory-clobber but NO counter drain.
static __device__ __forceinline__ void barrier_raw() {
    asm volatile("s_barrier" ::: "memory");
}
// Drain only LDS ops (epilogue visibility) — leaves vm (B DMA, C stores) alone.
static __device__ __forceinline__ void lgkm_drain() {
    asm volatile("s_waitcnt lgkmcnt(0)" ::: "memory");
}
// Counted vmcnt wait (literal N): vmem ops retire in order (m135), so
// vmcnt(N) == "all but the N youngest are complete".
#define VMCNT(n) asm volatile("s_waitcnt vmcnt(" #n ")" ::: "memory")

// Async global->LDS DMA, 16 B per lane (dest = wave base + lane*16).
static __device__ __forceinline__ void gload_lds16(const u8* g, char* l) {
    __builtin_amdgcn_global_load_lds(
        (const __attribute__((address_space(1))) unsigned int*)g,
        (__attribute__((address_space(3))) unsigned int*)l,
        16, 0, 0);
}

// ---------------------------------------------------------------------------
// B-only prep: Bt_fp8[n][k] = e4m3(B[k][n]), 32x32 LDS-transposed tiles.
// 1024 blocks, ~5 MB traffic (~2 us). Proven code.
// ---------------------------------------------------------------------------
__global__ __launch_bounds__(256)
void prep_b_kernel(const float* __restrict__ B, u8* __restrict__ Bt) {
    __shared__ float tile[32][33];
    const int tid = threadIdx.x;
    const int bid = (int)blockIdx.x;
    const int n0 = (bid & 31) * 32;
    const int k0 = (bid >> 5) * 32;
    const int tx = tid & 31;
    const int ty = tid >> 5;   // 0..7
#pragma unroll
    for (int i = 0; i < 32; i += 8)
        tile[ty + i][tx] = B[(size_t)(k0 + ty + i) * N_GLOB + n0 + tx];
    __syncthreads();
#pragma unroll
    for (int i = 0; i < 32; i += 8) {
        int w = __builtin_amdgcn_cvt_pk_fp8_f32(tile[tx][ty + i], 0.f, 0, false);
        Bt[(size_t)(n0 + ty + i) * K_GLOB + k0 + tx] = (u8)(w & 0xFF);
    }
}

// ---------------------------------------------------------------------------
// Fused GEMM: A f32 -> fp8 LDS panel (read once), Bt fp8 streamed, f32 C out.
//  - 512 threads = 8 waves: 2 row-groups (32 rows) x 4 col-groups (64 cols).
//    acc = 2x f32x16 = 32 VGPR. Grid 256 blocks (1/CU), LDS 128 KB.
//  - A panel: 64 x 1024 fp8 = 64 KB @0; swizzle invariant: within each 128B
//    kt-block, 16B position p of row r holds chunk p ^ (r&7).
//  - B: 2 x 32 KB dbuf @65536/@98304, global_load_lds w16, pre-swizzled src,
//    counted vmcnt, raw barriers (never drains prefetch in-loop).
//  - Epilogue per 256-col chunk: buf1 (just freed) becomes Cs [32][256] f32;
//    two 32-row halves, f32x4 nontemporal stores (proven-ideal WRITE_SIZE).
// ---------------------------------------------------------------------------
__global__ __launch_bounds__(512, 2)
void gemm_fused_lds_kernel(const float* __restrict__ A,
                           const u8* __restrict__ Bt,
                           float* __restrict__ C)
{
    __shared__ __attribute__((aligned(16))) char smem[131072];

    const int tid   = threadIdx.x;
    const int wave  = tid >> 6;      // 0..7
    const int lane  = tid & 63;
    const int wr    = wave >> 2;     // row group: rows wr*32 .. +31
    const int wcol  = wave & 3;      // col group: cols wcol*64 .. +63
    const int l32   = lane & 31;
    const int halfL = lane >> 5;     // k-half selector of the MFMA operand
    const int swz   = lane & 7;      // fragment row & 7

    const int m0 = (int)blockIdx.x * BM;

    // B staging map: lane L -> row (L>>3), LDS 16B position p = L&7 holding
    // global chunk c = p ^ (L>>3) (swizzle applied on the global source).
    const int srow = lane >> 3;
    const int sp   = lane & 7;
    const int sc   = sp ^ srow;

    const int scale1 = 0x7F7F7F7F;   // e8m0 127 = 2^0 in every byte
    const float LN2 = 0.69314718055994530942f;

    // Stage B tile for pipeline step v (chunk v>>3, kt v&7): 32 KB via
    // 4 gload_lds16 per thread. Wave w, issue s: rows ((s*8+w)*8 .. +8).
#define STAGE(v, bufsel)                                                      \
    {                                                                         \
        const int ktv = (v) & 7;                                              \
        const int chv = (v) >> 3;                                             \
        const u8* srcb = Bt + (size_t)(chv * BNC + srow) * K_GLOB             \
                            + ktv * 128 + sc * 16;                            \
        char* dstb = smem + 65536 + (bufsel) * 32768 + wave * 1024;           \
        _Pragma("unroll")                                                     \
        for (int s_ = 0; s_ < 4; ++s_)                                        \
            gload_lds16(srcb + (size_t)((s_ * 8 + wave) * 8) * K_GLOB,        \
                        dstb + s_ * 8192);                                    \
    }

    // ---- issue B tile 0 prefetch first (lands during the A phase)
    STAGE(0, 0);

    // ---- A phase: read the 64x1024 f32 panel ONCE (nontemporal, fully
    // coalesced: one wave instr = 4 KB = one full row), convert to fp8,
    // write swizzled 16B chunks to LDS. Wave w pass p -> row p*8+w (row&7==w),
    // so each wave-instr writes one full 1024B LDS row (conflict-free).
    {
        const int cpos = tid & 63;
        const int rw   = wave;              // row & 7 for this thread
#pragma unroll
        for (int p = 0; p < 8; ++p) {
            const int row = p * 8 + rw;
            const float* src = A + (size_t)(m0 + row) * K_GLOB + cpos * 16;
            f32x4 f0 = __builtin_nontemporal_load((const f32x4*)(src));
            f32x4 f1 = __builtin_nontemporal_load((const f32x4*)(src + 4));
            f32x4 f2 = __builtin_nontemporal_load((const f32x4*)(src + 8));
            f32x4 f3 = __builtin_nontemporal_load((const f32x4*)(src + 12));
            u32x4 o;
            o.x = cvt4_fp8(f0.x, f0.y, f0.z, f0.w);
            o.y = cvt4_fp8(f1.x, f1.y, f1.z, f1.w);
            o.z = cvt4_fp8(f2.x, f2.y, f2.z, f2.w);
            o.w = cvt4_fp8(f3.x, f3.y, f3.z, f3.w);
            const int pos = cpos ^ rw;      // low-3-bit XOR within kt-block
            *(u32x4*)(smem + row * 1024 + pos * 16) = o;
        }
    }
    __syncthreads();   // drains vm (A loads + B tile0 DMA) and lgkm (A writes)

    const char* aBase = smem + (size_t)(wr * 32 + l32) * 1024;

    for (int cc = 0; cc < NCH; ++cc) {
        f32x16 acc[2];
#pragma unroll
        for (int j = 0; j < 2; ++j)
#pragma unroll
            for (int r = 0; r < 16; ++r)
                acc[j][r] = 0.f;

        for (int kt = 0; kt < NKT; ++kt) {
            const int v = cc * NKT + kt;
            // prefetch step v+1; wait for tile v (counted: after the chunk
            // epilogue 8 stores are still pending -> 12; else 4).
            if (v + 1 < NT) {
                STAGE(v + 1, (v + 1) & 1);
                if (kt == 0) { VMCNT(12); } else { VMCNT(4); }
            } else {
                VMCNT(0);
            }
            barrier_raw();   // all waves' tile-v DMA landed

            const char* bBase = smem + 65536 + (v & 1) * 32768;
#pragma unroll
            for (int s = 0; s < 2; ++s) {       // two MX K=64 steps
                const int c0l = s * 4 + halfL * 2;
                const int p0 = ((c0l    ) ^ swz) * 16;
                const int p1 = ((c0l + 1) ^ swz) * 16;
                i32x8 af;
                {
                    u32x4 lo = *(const u32x4*)(aBase + kt * 128 + p0);
                    u32x4 hi = *(const u32x4*)(aBase + kt * 128 + p1);
                    af[0] = lo.x; af[1] = lo.y; af[2] = lo.z; af[3] = lo.w;
                    af[4] = hi.x; af[5] = hi.y; af[6] = hi.z; af[7] = hi.w;
                }
                i32x8 bf[2];
#pragma unroll
                for (int j = 0; j < 2; ++j) {
                    const char* bRow = bBase + (size_t)(wcol * 64 + j * 32 + l32) * 128;
                    u32x4 lo = *(const u32x4*)(bRow + p0);
                    u32x4 hi = *(const u32x4*)(bRow + p1);
                    bf[j][0] = lo.x; bf[j][1] = lo.y; bf[j][2] = lo.z; bf[j][3] = lo.w;
                    bf[j][4] = hi.x; bf[j][5] = hi.y; bf[j][6] = hi.z; bf[j][7] = hi.w;
                }
#pragma unroll
                for (int j = 0; j < 2; ++j)
                    acc[j] = __builtin_amdgcn_mfma_scale_f32_32x32x64_f8f6f4(
                        af, bf[j], acc[j],
                        0 /*cbsz: A=fp8 e4m3*/, 0 /*blgp: B=fp8 e4m3*/,
                        0, scale1, 0, scale1);
            }
            barrier_raw();   // reads done before buf(v&1) is overwritten
        }

        // ---- chunk epilogue: buf1 just freed (last compute used it; the
        // in-flight prefetch targets buf0) -> use as Cs [32][256] f32.
        // Two 32-row halves; lgkm-only drains keep B DMA + C stores in flight.
        float* Cs = (float*)(smem + 98304);
        const int n0c = cc * BNC;
        const int crow = tid >> 4;          // 0..31
        const int cq   = tid & 15;
#pragma unroll
        for (int h = 0; h < 2; ++h) {
            if (wr == h) {
#pragma unroll
                for (int j = 0; j < 2; ++j) {
                    const int col = wcol * 64 + j * 32 + l32;
#pragma unroll
                    for (int r = 0; r < 16; ++r) {
                        const int row32 = (r & 3) + 8 * (r >> 2) + 4 * halfL;
                        float vv = fmaxf(acc[j][r], 1.17549435e-38f);
                        Cs[row32 * 256 + col] = __log2f(vv) * LN2;
                    }
                }
            }
            lgkm_drain();
            barrier_raw();   // Cs visible to all waves
#pragma unroll
            for (int i = 0; i < 4; ++i) {
                f32x4 vv = *(const f32x4*)&Cs[crow * 256 + cq * 4 + 64 * i];
                __builtin_nontemporal_store(vv,
                    (f32x4*)&C[(size_t)(m0 + h * 32 + crow) * N_GLOB
                               + n0c + cq * 4 + 64 * i]);
            }
            lgkm_drain();
            barrier_raw();   // Cs reads done before h=1 overwrite / next STAGE
        }
    }
#undef STAGE
}

// ---------------------------------------------------------------------------
// Fallback (round-1 kernel): fused fp32->bf16 staging, padded LDS.
// Used only if ws can't hold Bt (1 MiB).
// ---------------------------------------------------------------------------
#define FBM 128
#define FBN 128
#define LDK 40
__global__ __launch_bounds__(256)
void logmm_fused_kernel(const float* __restrict__ A,
                        const float* __restrict__ Bf,
                        float* __restrict__ C)
{
    __shared__ u16 As[FBM][LDK];
    __shared__ u16 Bs[FBN][LDK];

    const int tid  = threadIdx.x;
    const int lane = tid & 63;
    const int wave = tid >> 6;
    const int wr   = wave >> 1;
    const int wc   = wave & 1;
    const int quad = lane >> 4;
    const int l16  = lane & 15;

    const int m0 = blockIdx.y * FBM;
    const int n0 = blockIdx.x * FBN;

    f32x4 acc[4][4];
#pragma unroll
    for (int i = 0; i < 4; ++i)
#pragma unroll
        for (int j = 0; j < 4; ++j)
            acc[i][j] = f32x4{0.f, 0.f, 0.f, 0.f};

    const int ga_row = tid >> 2;
    const int ga_c8  = (tid & 3) * 8;
    const int fb_nt = tid >> 3;
    const int fb_kt = tid & 7;

    for (int kt = 0; kt < K_GLOB / 32; ++kt) {
        const int k0 = kt * 32;
#pragma unroll
        for (int s = 0; s < 2; ++s) {
            const int row = ga_row + s * 64;
            const float* src = A + (size_t)(m0 + row) * K_GLOB + k0 + ga_c8;
            f32x4 f0 = *(const f32x4*)src;
            f32x4 f1 = *(const f32x4*)(src + 4);
            u32x4 o;
            o.x = pack2_bf16(f0.x, f0.y);
            o.y = pack2_bf16(f0.z, f0.w);
            o.z = pack2_bf16(f1.x, f1.y);
            o.w = pack2_bf16(f1.z, f1.w);
            *(u32x4*)&As[row][ga_c8] = o;
        }
        {
            f32x4 r0 = *(const f32x4*)(Bf + (size_t)(k0 + fb_kt * 4 + 0) * N_GLOB + n0 + fb_nt * 4);
            f32x4 r1 = *(const f32x4*)(Bf + (size_t)(k0 + fb_kt * 4 + 1) * N_GLOB + n0 + fb_nt * 4);
            f32x4 r2 = *(const f32x4*)(Bf + (size_t)(k0 + fb_kt * 4 + 2) * N_GLOB + n0 + fb_nt * 4);
            f32x4 r3 = *(const f32x4*)(Bf + (size_t)(k0 + fb_kt * 4 + 3) * N_GLOB + n0 + fb_nt * 4);
#pragma unroll
            for (int j = 0; j < 4; ++j) {
                u32x2 o;
                o.x = pack2_bf16(r0[j], r1[j]);
                o.y = pack2_bf16(r2[j], r3[j]);
                *(u32x2*)&Bs[fb_nt * 4 + j][fb_kt * 4] = o;
            }
        }

        __syncthreads();

        bf16x8 af[4], bfr[4];
#pragma unroll
        for (int i = 0; i < 4; ++i)
            af[i] = __builtin_bit_cast(bf16x8, *(const u32x4*)&As[wr * 64 + i * 16 + l16][quad * 8]);
#pragma unroll
        for (int j = 0; j < 4; ++j)
            bfr[j] = __builtin_bit_cast(bf16x8, *(const u32x4*)&Bs[wc * 64 + j * 16 + l16][quad * 8]);

#pragma unroll
        for (int i = 0; i < 4; ++i)
#pragma unroll
            for (int j = 0; j < 4; ++j)
                acc[i][j] = __builtin_amdgcn_mfma_f32_16x16x32_bf16(af[i], bfr[j], acc[i][j], 0, 0, 0);

        __syncthreads();
    }

    const float LN2 = 0.69314718055994530942f;
#pragma unroll
    for (int i = 0; i < 4; ++i) {
#pragma unroll
        for (int j = 0; j < 4; ++j) {
            const int col = n0 + wc * 64 + j * 16 + l16;
#pragma unroll
            for (int r = 0; r < 4; ++r) {
                const int row = m0 + wr * 64 + i * 16 + quad * 4 + r;
                float v = fmaxf(acc[i][j][r], 1.17549435e-38f);
                C[(size_t)row * N_GLOB + col] = __log2f(v) * LN2;
            }
        }
    }
}

extern "C" void kernel_launch(void* const* d_in, const int* in_sizes, int n_in,
                              void* d_out, int out_size, void* d_ws, size_t ws_size,
                              hipStream_t stream) {
    const float* A = (const float*)d_in[0];   // x: [16384,1024]
    const float* B = (const float*)d_in[1];   // matrix: [1024,1024]
    float* C = (float*)d_out;

    const size_t bt_bytes = (size_t)N_GLOB * K_GLOB;        // 1 MiB fp8

    if (ws_size >= bt_bytes) {
        u8* Bt = (u8*)d_ws;
        prep_b_kernel<<<1024, 256, 0, stream>>>(B, Bt);
        gemm_fused_lds_kernel<<<M_GLOB / BM, 512, 0, stream>>>(A, Bt, C);
    } else {
        logmm_fused_kernel<<<dim3(N_GLOB / FBN, M_GLOB / FBM), 256, 0, stream>>>(A, B, C);
    }
}